// Round 6
// baseline (226.192 us; speedup 1.0000x reference)
//
#include <hip/hip_runtime.h>
#include <math.h>

// B=32, F=1000, D=1024; OUT = 1+22+1+22+1+128 = 175
#define D_DIM  1024
#define OUT_N  175
#define HID_N  128
#define BM     64
#define BK     32
#define NT     (D_DIM / BK)     // 32 K-steps
#define LDK    40               // LDS A row stride (shorts): 32 k + 8 pad = 80 B
#define NFRAG  11               // N tiles of 16 (176 padded)
#define FRAG_STRIDE 512         // shorts per (j,t) B-fragment: 64 lanes * 8

#define V_OFF   1
#define VG_OFF  23
#define N_OFF   24
#define NG_OFF  46
#define HF_OFF  47

#define LOG_F0_MIN 4.3820266346738812f   // ln(80)
#define LOG_F0_MAX 6.9077552789821368f   // ln(1000)
#define PI_F       3.14159265358979323846f

typedef __attribute__((ext_vector_type(8))) short s16x8;   // 8 bf16 = 4 VGPR MFMA frag
typedef __attribute__((ext_vector_type(4))) short s16x4;
typedef __attribute__((ext_vector_type(4))) float f32x4;

// fp32 -> bf16 bits, round-to-nearest-even (pure integer)
static __device__ __forceinline__ short f2bf(float f) {
    unsigned u = __float_as_uint(f);
    unsigned r = (u + 0x7fffu + ((u >> 16) & 1u)) >> 16;
    return (short)r;
}
static __device__ __forceinline__ float bf2f(short s) {
    return __uint_as_float(((unsigned)(unsigned short)s) << 16);
}

// ---------- pre-kernel: W (fp32) -> bf16 hi/lo in MFMA-FRAGMENT order ----------
// layout: frag (j,t) at ((j*NT)+t)*FRAG_STRIDE; within: lane*8 + e
//   value = W[n=16j+(lane&15)][k = 32t + (lane>>4)*8 + e]   (zeros for n>=175)
__global__ __launch_bounds__(64) void build_wfrag(
    const float* __restrict__ W, short* __restrict__ whiF, short* __restrict__ wloF)
{
    const int ft   = blockIdx.x;           // j*32 + t, 0..351
    const int j    = ft >> 5;
    const int t    = ft & 31;
    const int lane = threadIdx.x;
    const int n    = 16 * j + (lane & 15);
    const int k    = 32 * t + (lane >> 4) * 8;

    float v[8];
    if (n < OUT_N) {
        float4 p0 = *(const float4*)(W + (size_t)n * D_DIM + k);
        float4 p1 = *(const float4*)(W + (size_t)n * D_DIM + k + 4);
        v[0] = p0.x; v[1] = p0.y; v[2] = p0.z; v[3] = p0.w;
        v[4] = p1.x; v[5] = p1.y; v[6] = p1.z; v[7] = p1.w;
    } else {
        #pragma unroll
        for (int e = 0; e < 8; ++e) v[e] = 0.f;
    }
    s16x8 hv, lv;
    #pragma unroll
    for (int e = 0; e < 8; ++e) {
        short hb = f2bf(v[e]);
        hv[e] = hb;
        lv[e] = f2bf(v[e] - bf2f(hb));
    }
    const size_t off = ((size_t)ft * 64 + lane) * 8;
    *(s16x8*)(whiF + off) = hv;
    *(s16x8*)(wloF + off) = lv;
}

// ---------- main fused kernel ----------
// LDS union: { AhiS[64][40]s + AloS[64][40]s = 10240 B }  U  { yS[64][49] f32 = 12544 B }
#define SMEM_BYTES 12544

__global__ __launch_bounds__(512, 4) void glottal_main(
    const float* __restrict__ h, const short* __restrict__ whiF,
    const short* __restrict__ wloF, const float* __restrict__ bias,
    float* __restrict__ out, int R)
{
    __shared__ __align__(16) char smem[SMEM_BYTES];
    short* AhiS = (short*)smem;              // [64][40]
    short* AloS = AhiS + BM * LDK;           // [64][40]
    float (*yS)[49] = (float (*)[49])smem;   // epilogue union (cols 0..46)

    const int tid  = threadIdx.x;
    const int r0   = blockIdx.x * BM;

    const int lane = tid & 63;
    const int wid  = tid >> 6;       // 0..7
    const int c    = lane & 15;
    const int kg   = lane >> 4;
    const int mh   = wid >> 2;       // m-half: rows 32*mh..
    const int jg   = wid & 3;        // j-group: j = 3*jg + jj
    const int jcnt = (jg < 3) ? 3 : 2;

    // A staging: 512 threads == 64 rows x 8 float4 -> exactly 1 float4/thread
    const int rA  = tid >> 3;            // 0..63
    const int kqA = (tid & 7) << 2;      // 0,4,..,28
    int gA = r0 + rA; if (gA >= R) gA = R - 1;
    const float* hP = h + (size_t)gA * D_DIM + kqA;

    // B fragment pointers (global, L2-resident)
    const short* bhP[3];
    const short* blP[3];
    #pragma unroll
    for (int jj = 0; jj < 3; ++jj) {
        int j = 3 * jg + jj; if (j > NFRAG - 1) j = NFRAG - 1;   // clamp (guarded anyway)
        bhP[jj] = whiF + (size_t)j * NT * FRAG_STRIDE + lane * 8;
        blP[jj] = wloF + (size_t)j * NT * FRAG_STRIDE + lane * 8;
    }

    f32x4 acc[2][3];
    #pragma unroll
    for (int mm = 0; mm < 2; ++mm)
        #pragma unroll
        for (int jj = 0; jj < 3; ++jj) acc[mm][jj] = f32x4{0.f, 0.f, 0.f, 0.f};

    // ---- prologue: load tile 0 ----
    float4 aC = *(const float4*)(hP);
    s16x8 bhC[3], blC[3];
    #pragma unroll
    for (int jj = 0; jj < 3; ++jj) if (jj < jcnt) {
        bhC[jj] = *(const s16x8*)(bhP[jj]);
        blC[jj] = *(const s16x8*)(blP[jj]);
    }

    for (int t = 0; t < NT; ++t) {
        // ---- split current A regs -> LDS ----
        {
            s16x4 hv, lv;
            hv.x = f2bf(aC.x); lv.x = f2bf(aC.x - bf2f(hv.x));
            hv.y = f2bf(aC.y); lv.y = f2bf(aC.y - bf2f(hv.y));
            hv.z = f2bf(aC.z); lv.z = f2bf(aC.z - bf2f(hv.z));
            hv.w = f2bf(aC.w); lv.w = f2bf(aC.w - bf2f(hv.w));
            *(s16x4*)(AhiS + rA * LDK + kqA) = hv;
            *(s16x4*)(AloS + rA * LDK + kqA) = lv;
        }
        __syncthreads();

        // ---- prefetch next tile (A fp32 + B frags) under the MFMAs ----
        float4 aN;
        s16x8 bhN[3], blN[3];
        const bool more = (t + 1 < NT);
        if (more) {
            aN = *(const float4*)(hP + (t + 1) * BK);
            #pragma unroll
            for (int jj = 0; jj < 3; ++jj) if (jj < jcnt) {
                bhN[jj] = *(const s16x8*)(bhP[jj] + (size_t)(t + 1) * FRAG_STRIDE);
                blN[jj] = *(const s16x8*)(blP[jj] + (size_t)(t + 1) * FRAG_STRIDE);
            }
        }

        // ---- A fragment reads (2-way bank aliasing only: free) ----
        s16x8 ah[2], al[2];
        #pragma unroll
        for (int mm = 0; mm < 2; ++mm) {
            const int ro = (32 * mh + 16 * mm + c) * LDK + kg * 8;
            ah[mm] = *(const s16x8*)(AhiS + ro);
            al[mm] = *(const s16x8*)(AloS + ro);
        }

        // ---- 3-pass split-bf16 MFMA ----
        #pragma unroll
        for (int jj = 0; jj < 3; ++jj) if (jj < jcnt) {
            #pragma unroll
            for (int mm = 0; mm < 2; ++mm) {
                acc[mm][jj] = __builtin_amdgcn_mfma_f32_16x16x32_bf16(ah[mm], bhC[jj], acc[mm][jj], 0, 0, 0);
                acc[mm][jj] = __builtin_amdgcn_mfma_f32_16x16x32_bf16(ah[mm], blC[jj], acc[mm][jj], 0, 0, 0);
                acc[mm][jj] = __builtin_amdgcn_mfma_f32_16x16x32_bf16(al[mm], bhC[jj], acc[mm][jj], 0, 0, 0);
            }
        }
        __syncthreads();

        if (more) {
            aC = aN;
            #pragma unroll
            for (int jj = 0; jj < 3; ++jj) if (jj < jcnt) {
                bhC[jj] = bhN[jj];
                blC[jj] = blN[jj];
            }
        }
    }

    const size_t Rz = (size_t)R;

    // ---- epilogue: h_feat direct from regs; cols 0..46 via small yS ----
    // D frag: col = 16j + c, row = 32*mh + 16*mm + 4*kg + r
    #pragma unroll
    for (int jj = 0; jj < 3; ++jj) if (jj < jcnt) {
        const int j   = 3 * jg + jj;
        const int col = 16 * j + c;
        const float bb = (col < OUT_N) ? bias[col] : 0.f;
        #pragma unroll
        for (int mm = 0; mm < 2; ++mm) {
            const int rb = 32 * mh + 16 * mm + (kg << 2);
            if (col >= HF_OFF && col < OUT_N) {
                #pragma unroll
                for (int r = 0; r < 4; ++r) {
                    int gr = r0 + rb + r;
                    if (gr < R)
                        out[Rz + (size_t)gr * HID_N + (col - HF_OFF)] = acc[mm][jj][r] + bb;
                }
            } else if (col < HF_OFF) {
                #pragma unroll
                for (int r = 0; r < 4; ++r)
                    yS[rb + r][col] = acc[mm][jj][r] + bb;
            }
        }
    }
    __syncthreads();

    // ---- scalars + LPC: 2 threads/row (half 0 = voice+f0, half 1 = noise) ----
    if (tid < 2 * BM) {
        const int rr   = tid >> 1;
        const int half = tid & 1;
        const int gr   = r0 + rr;
        if (gr < R) {
            const float* yrow = yS[rr];

            if (half == 0) {
                float s = 1.f / (1.f + expf(-yrow[0]));
                out[gr] = expf(s * (LOG_F0_MAX - LOG_F0_MIN) + LOG_F0_MIN);
            }

            const int lbase = half ? N_OFF  : V_OFF;
            const int gidx  = half ? NG_OFF : VG_OFF;
            float*    gout  = out + (half ? Rz * 152 : Rz * 129);
            float*    lout  = out + (half ? Rz * 153 : Rz * 130);

            gout[gr] = expf(yrow[gidx]);

            float poly[23];
            poly[0] = 1.f;
            #pragma unroll
            for (int j = 1; j < 23; ++j) poly[j] = 0.f;

            #pragma unroll
            for (int i = 0; i < 11; ++i) {
                float l0  = yrow[lbase + 2 * i];
                float l1  = yrow[lbase + 2 * i + 1];
                float mag = 0.99f / (1.f + expf(-l0));
                float ph  = PI_F   / (1.f + expf(-l1));
                float a1  = -2.f * mag * cosf(ph);
                float a2  = mag * mag;
                #pragma unroll
                for (int j = 22; j >= 2; --j)
                    poly[j] = fmaf(a1, poly[j - 1], fmaf(a2, poly[j - 2], poly[j]));
                poly[1] = fmaf(a1, poly[0], poly[1]);
            }

            #pragma unroll
            for (int j = 0; j < 22; ++j)
                lout[(size_t)gr * 22 + j] = poly[j + 1];
        }
    }
}

extern "C" void kernel_launch(void* const* d_in, const int* in_sizes, int n_in,
                              void* d_out, int out_size, void* d_ws, size_t ws_size,
                              hipStream_t stream) {
    const float* h    = (const float*)d_in[0];
    const float* W    = (const float*)d_in[1];
    const float* bias = (const float*)d_in[2];
    float* out        = (float*)d_out;

    const int R = in_sizes[0] / D_DIM;          // 32000
    const int blocks = (R + BM - 1) / BM;       // 500

    short* whiF = (short*)d_ws;                           // 352*512 shorts
    short* wloF = whiF + (size_t)NFRAG * NT * FRAG_STRIDE; // total 720896 B

    build_wfrag<<<NFRAG * NT, 64, 0, stream>>>(W, whiF, wloF);
    glottal_main<<<blocks, 512, 0, stream>>>(h, whiF, wloF, bias, out, R);
}

// Round 7
// 214.971 us; speedup vs baseline: 1.0522x; 1.0522x over previous
//
#include <hip/hip_runtime.h>
#include <math.h>

// B=32, F=1000, D=1024; OUT = 1+22+1+22+1+128 = 175
#define D_DIM  1024
#define OUT_N  175
#define HID_N  128
#define BM     64
#define NT     32               // 32-k subtiles over full K
#define NFRAG  11               // N tiles of 16 (176 padded)
#define FRAG_STRIDE 512         // shorts per (j,t) B-fragment: 64 lanes * 8
#define CH     128              // chunk K size
#define NCH    (D_DIM / CH)     // 8 chunks
#define TPC    4                // 32-k subtiles per chunk
#define SUBT   2576             // shorts per LDS subtile: 64*40 + 16 pad

#define V_OFF   1
#define VG_OFF  23
#define N_OFF   24
#define NG_OFF  46
#define HF_OFF  47

#define LOG_F0_MIN 4.3820266346738812f   // ln(80)
#define LOG_F0_MAX 6.9077552789821368f   // ln(1000)
#define PI_F       3.14159265358979323846f

typedef __attribute__((ext_vector_type(8))) short s16x8;   // 8 bf16 = 4 VGPR MFMA frag
typedef __attribute__((ext_vector_type(4))) short s16x4;
typedef __attribute__((ext_vector_type(4))) float f32x4;

// fp32 -> bf16 bits, round-to-nearest-even (pure integer)
static __device__ __forceinline__ short f2bf(float f) {
    unsigned u = __float_as_uint(f);
    unsigned r = (u + 0x7fffu + ((u >> 16) & 1u)) >> 16;
    return (short)r;
}
static __device__ __forceinline__ float bf2f(short s) {
    return __uint_as_float(((unsigned)(unsigned short)s) << 16);
}

// ---------- pre-kernel: W (fp32) -> bf16 hi/lo in MFMA-FRAGMENT order ----------
// frag (j,t) at ((j*NT)+t)*FRAG_STRIDE; within: lane*8+e
//   = W[n=16j+(lane&15)][k=32t+(lane>>4)*8+e]  (zeros for n>=175)
__global__ __launch_bounds__(64) void build_wfrag(
    const float* __restrict__ W, short* __restrict__ whiF, short* __restrict__ wloF)
{
    const int ft   = blockIdx.x;           // j*32+t
    const int j    = ft >> 5;
    const int t    = ft & 31;
    const int lane = threadIdx.x;
    const int n    = 16 * j + (lane & 15);
    const int k    = 32 * t + (lane >> 4) * 8;

    float v[8];
    if (n < OUT_N) {
        float4 p0 = *(const float4*)(W + (size_t)n * D_DIM + k);
        float4 p1 = *(const float4*)(W + (size_t)n * D_DIM + k + 4);
        v[0] = p0.x; v[1] = p0.y; v[2] = p0.z; v[3] = p0.w;
        v[4] = p1.x; v[5] = p1.y; v[6] = p1.z; v[7] = p1.w;
    } else {
        #pragma unroll
        for (int e = 0; e < 8; ++e) v[e] = 0.f;
    }
    s16x8 hv, lv;
    #pragma unroll
    for (int e = 0; e < 8; ++e) {
        short hb = f2bf(v[e]);
        hv[e] = hb;
        lv[e] = f2bf(v[e] - bf2f(hb));
    }
    const size_t off = ((size_t)ft * 64 + lane) * 8;
    *(s16x8*)(whiF + off) = hv;
    *(s16x8*)(wloF + off) = lv;
}

// ---------- main fused kernel ----------
// LDS: AhiS[TPC*SUBT] + AloS[TPC*SUBT] shorts = 41216 B; epilogue yS[64][49] unioned
#define SMEM_BYTES (2 * TPC * SUBT * 2)

__global__ __launch_bounds__(256, 2) void glottal_main(
    const float* __restrict__ h, const short* __restrict__ whiF,
    const short* __restrict__ wloF, const float* __restrict__ bias,
    float* __restrict__ out, int R)
{
    __shared__ __align__(16) char smem[SMEM_BYTES];
    short* AhiS = (short*)smem;
    short* AloS = AhiS + TPC * SUBT;
    float (*yS)[49] = (float (*)[49])smem;

    const int tid  = threadIdx.x;
    const int r0   = blockIdx.x * BM;

    const int lane = tid & 63;
    const int wid  = tid >> 6;       // 0..3 = jg
    const int c    = lane & 15;
    const int kg   = lane >> 4;
    const int jg   = wid;
    const int jcnt = (jg < 3) ? 3 : 2;

    // staging map: load i covers rows srow+8i, 16B col scf*16B of the 512B chunk-row
    const int srow = tid >> 5;       // 0..7
    const int scf  = tid & 31;       // 0..31 (float4 index within chunk-row)
    // LDS write target (per load i): subtile t4=scf>>3, within-k offset (scf&7)*4
    const int st4  = scf >> 3;
    const int sko  = (scf & 7) << 2;

    // B fragment pointers (global, fragment-ordered, L2-resident)
    const short* bhP[3];
    const short* blP[3];
    #pragma unroll
    for (int jj = 0; jj < 3; ++jj) {
        int j = 3 * jg + jj; if (j > NFRAG - 1) j = NFRAG - 1;
        bhP[jj] = whiF + (size_t)j * NT * FRAG_STRIDE + lane * 8;
        blP[jj] = wloF + (size_t)j * NT * FRAG_STRIDE + lane * 8;
    }

    f32x4 acc[4][3];
    #pragma unroll
    for (int mm = 0; mm < 4; ++mm)
        #pragma unroll
        for (int jj = 0; jj < 3; ++jj) acc[mm][jj] = f32x4{0.f, 0.f, 0.f, 0.f};

    // per-i global row pointers (clamped once)
    const float* hP[8];
    #pragma unroll
    for (int i = 0; i < 8; ++i) {
        int gr = r0 + srow + 8 * i; if (gr >= R) gr = R - 1;
        hP[i] = h + (size_t)gr * D_DIM + scf * 4;
    }

    float4 sA[8];

    // ---- prologue: load+commit chunk 0, issue chunk 1 ----
    #pragma unroll
    for (int i = 0; i < 8; ++i) sA[i] = *(const float4*)(hP[i]);
    #pragma unroll
    for (int i = 0; i < 8; ++i) {
        const int base = st4 * SUBT + (srow + 8 * i) * 40 + sko;
        s16x4 hv, lv;
        hv.x = f2bf(sA[i].x); lv.x = f2bf(sA[i].x - bf2f(hv.x));
        hv.y = f2bf(sA[i].y); lv.y = f2bf(sA[i].y - bf2f(hv.y));
        hv.z = f2bf(sA[i].z); lv.z = f2bf(sA[i].z - bf2f(hv.z));
        hv.w = f2bf(sA[i].w); lv.w = f2bf(sA[i].w - bf2f(hv.w));
        *(s16x4*)(AhiS + base) = hv;
        *(s16x4*)(AloS + base) = lv;
    }
    #pragma unroll
    for (int i = 0; i < 8; ++i) sA[i] = *(const float4*)(hP[i] + CH);
    __syncthreads();

    for (int ch = 0; ch < NCH; ++ch) {
        // ---- compute chunk ch: 4 subtiles x (A ds_read + B L2 prefetch + 36 MFMA) ----
        s16x8 bhC[3], blC[3];
        const int tg0 = ch * TPC;
        #pragma unroll
        for (int jj = 0; jj < 3; ++jj) if (jj < jcnt) {
            bhC[jj] = *(const s16x8*)(bhP[jj] + (size_t)tg0 * FRAG_STRIDE);
            blC[jj] = *(const s16x8*)(blP[jj] + (size_t)tg0 * FRAG_STRIDE);
        }
        #pragma unroll
        for (int t4 = 0; t4 < TPC; ++t4) {
            s16x8 ah[4], al[4];
            #pragma unroll
            for (int mm = 0; mm < 4; ++mm) {
                const int off = t4 * SUBT + (16 * mm + c) * 40 + kg * 8;
                ah[mm] = *(const s16x8*)(AhiS + off);
                al[mm] = *(const s16x8*)(AloS + off);
            }
            s16x8 bhN[3], blN[3];
            if (t4 < TPC - 1) {
                #pragma unroll
                for (int jj = 0; jj < 3; ++jj) if (jj < jcnt) {
                    bhN[jj] = *(const s16x8*)(bhP[jj] + (size_t)(tg0 + t4 + 1) * FRAG_STRIDE);
                    blN[jj] = *(const s16x8*)(blP[jj] + (size_t)(tg0 + t4 + 1) * FRAG_STRIDE);
                }
            }
            #pragma unroll
            for (int jj = 0; jj < 3; ++jj) if (jj < jcnt) {
                #pragma unroll
                for (int mm = 0; mm < 4; ++mm) {
                    acc[mm][jj] = __builtin_amdgcn_mfma_f32_16x16x32_bf16(ah[mm], bhC[jj], acc[mm][jj], 0, 0, 0);
                    acc[mm][jj] = __builtin_amdgcn_mfma_f32_16x16x32_bf16(ah[mm], blC[jj], acc[mm][jj], 0, 0, 0);
                    acc[mm][jj] = __builtin_amdgcn_mfma_f32_16x16x32_bf16(al[mm], bhC[jj], acc[mm][jj], 0, 0, 0);
                }
            }
            if (t4 < TPC - 1) {
                #pragma unroll
                for (int jj = 0; jj < 3; ++jj) if (jj < jcnt) {
                    bhC[jj] = bhN[jj]; blC[jj] = blN[jj];
                }
            }
        }
        __syncthreads();   // everyone done reading LDS chunk ch (also guards epilogue yS)

        if (ch < NCH - 1) {
            // ---- commit chunk ch+1 (regs loaded one full compute phase ago) ----
            #pragma unroll
            for (int i = 0; i < 8; ++i) {
                const int base = st4 * SUBT + (srow + 8 * i) * 40 + sko;
                s16x4 hv, lv;
                hv.x = f2bf(sA[i].x); lv.x = f2bf(sA[i].x - bf2f(hv.x));
                hv.y = f2bf(sA[i].y); lv.y = f2bf(sA[i].y - bf2f(hv.y));
                hv.z = f2bf(sA[i].z); lv.z = f2bf(sA[i].z - bf2f(hv.z));
                hv.w = f2bf(sA[i].w); lv.w = f2bf(sA[i].w - bf2f(hv.w));
                *(s16x4*)(AhiS + base) = hv;
                *(s16x4*)(AloS + base) = lv;
            }
            if (ch < NCH - 2) {
                #pragma unroll
                for (int i = 0; i < 8; ++i)
                    sA[i] = *(const float4*)(hP[i] + (size_t)(ch + 2) * CH);
            }
            __syncthreads();
        }
    }

    const size_t Rz = (size_t)R;

    // ---- epilogue: h_feat direct from regs; cols 0..46 via small yS ----
    // D frag: col = 16j + c, row = 16*mm + 4*kg + r
    #pragma unroll
    for (int jj = 0; jj < 3; ++jj) if (jj < jcnt) {
        const int j   = 3 * jg + jj;
        const int col = 16 * j + c;
        const float bb = (col < OUT_N) ? bias[col] : 0.f;
        #pragma unroll
        for (int mm = 0; mm < 4; ++mm) {
            const int rb = 16 * mm + (kg << 2);
            if (col >= HF_OFF && col < OUT_N) {
                #pragma unroll
                for (int r = 0; r < 4; ++r) {
                    int gr = r0 + rb + r;
                    if (gr < R)
                        out[Rz + (size_t)gr * HID_N + (col - HF_OFF)] = acc[mm][jj][r] + bb;
                }
            } else if (col < HF_OFF) {
                #pragma unroll
                for (int r = 0; r < 4; ++r)
                    yS[rb + r][col] = acc[mm][jj][r] + bb;
            }
        }
    }
    __syncthreads();

    // ---- scalars + LPC: 2 threads/row (half 0 = voice+f0, half 1 = noise) ----
    if (tid < 2 * BM) {
        const int rr   = tid >> 1;
        const int half = tid & 1;
        const int gr   = r0 + rr;
        if (gr < R) {
            const float* yrow = yS[rr];

            if (half == 0) {
                float s = 1.f / (1.f + expf(-yrow[0]));
                out[gr] = expf(s * (LOG_F0_MAX - LOG_F0_MIN) + LOG_F0_MIN);
            }

            const int lbase = half ? N_OFF  : V_OFF;
            const int gidx  = half ? NG_OFF : VG_OFF;
            float*    gout  = out + (half ? Rz * 152 : Rz * 129);
            float*    lout  = out + (half ? Rz * 153 : Rz * 130);

            gout[gr] = expf(yrow[gidx]);

            float poly[23];
            poly[0] = 1.f;
            #pragma unroll
            for (int j = 1; j < 23; ++j) poly[j] = 0.f;

            #pragma unroll
            for (int i = 0; i < 11; ++i) {
                float l0  = yrow[lbase + 2 * i];
                float l1  = yrow[lbase + 2 * i + 1];
                float mag = 0.99f / (1.f + expf(-l0));
                float ph  = PI_F   / (1.f + expf(-l1));
                float a1  = -2.f * mag * cosf(ph);
                float a2  = mag * mag;
                #pragma unroll
                for (int j = 22; j >= 2; --j)
                    poly[j] = fmaf(a1, poly[j - 1], fmaf(a2, poly[j - 2], poly[j]));
                poly[1] = fmaf(a1, poly[0], poly[1]);
            }

            #pragma unroll
            for (int j = 0; j < 22; ++j)
                lout[(size_t)gr * 22 + j] = poly[j + 1];
        }
    }
}

extern "C" void kernel_launch(void* const* d_in, const int* in_sizes, int n_in,
                              void* d_out, int out_size, void* d_ws, size_t ws_size,
                              hipStream_t stream) {
    const float* h    = (const float*)d_in[0];
    const float* W    = (const float*)d_in[1];
    const float* bias = (const float*)d_in[2];
    float* out        = (float*)d_out;

    const int R = in_sizes[0] / D_DIM;          // 32000
    const int blocks = (R + BM - 1) / BM;       // 500

    short* whiF = (short*)d_ws;                            // 352*512 shorts
    short* wloF = whiF + (size_t)NFRAG * NT * FRAG_STRIDE; // total 720896 B

    build_wfrag<<<NFRAG * NT, 64, 0, stream>>>(W, whiF, wloF);
    glottal_main<<<blocks, 256, 0, stream>>>(h, whiF, wloF, bias, out, R);
}